// Round 3
// baseline (3102.657 us; speedup 1.0000x reference)
//
#include <hip/hip_runtime.h>

typedef _Float16 h8 __attribute__((ext_vector_type(8)));
typedef float v4f __attribute__((ext_vector_type(4)));
typedef unsigned long long u64;

#define B_  256
#define T_  512
#define I_  64
#define H_  512
#define K_  576   // H_ + I_ : concatenated [h | x] inner dim

// workspace layout (bytes)
#define OFF_WCAT  0                                   // [2048][576] f16  (Whh | Wih)
#define OFF_BIAS  (OFF_WCAT + 2048*K_*2)              // [2048] f32 (b_ih+b_hh)
#define OFF_X16   (OFF_BIAS + 2048*4)                 // [512][256][64] f16 (t-major)
#define OFF_H0    (OFF_X16 + 512*256*64*2)            // [256][512] f16
#define OFF_H1    (OFF_H0 + 256*512*2)                // [256][512] f16
#define OFF_SNT   (OFF_H1 + 256*512*2)                // [16 btile][32 jtile] u32

__device__ __forceinline__ float sigf(float x) {
    float e = __builtin_amdgcn_exp2f(-1.442695041f * x);
    return __builtin_amdgcn_rcpf(1.f + e);
}
__device__ __forceinline__ float tanhf_(float x) {
    float e = __builtin_amdgcn_exp2f(2.885390082f * x);  // exp(2x)
    return 1.f - 2.f * __builtin_amdgcn_rcpf(e + 1.f);
}

union Pack4 { _Float16 f[4]; u64 u; };
union HU    { u64 u[2]; h8 v; };

__global__ void prep_w(const float* __restrict__ Wih, const float* __restrict__ Whh,
                       const float* __restrict__ bih, const float* __restrict__ bhh,
                       _Float16* __restrict__ Wcat, float* __restrict__ bias,
                       _Float16* __restrict__ h0, unsigned* __restrict__ snt) {
    int idx = blockIdx.x * 256 + threadIdx.x;          // grid covers 2048*512
    {
        int row = idx >> 9, col = idx & 511;
        Wcat[(size_t)row * K_ + col] = (_Float16)Whh[idx];
    }
    if (idx < 2048 * 64) {
        int row = idx >> 6, col = idx & 63;
        Wcat[(size_t)row * K_ + H_ + col] = (_Float16)Wih[idx];
    }
    if (idx < 2048) bias[idx] = bih[idx] + bhh[idx];
    // h0 zeros + sentinels must be visible at the IF$ coherence point
    if (idx < 32768)
        __hip_atomic_store((u64*)h0 + idx, 0ull,
                           __ATOMIC_RELAXED, __HIP_MEMORY_SCOPE_AGENT);
    if (idx < 512)
        __hip_atomic_store(snt + idx, 0u, __ATOMIC_RELAXED, __HIP_MEMORY_SCOPE_AGENT);
}

__global__ void prep_x(const float* __restrict__ x, _Float16* __restrict__ x16) {
    int idx = blockIdx.x * 256 + threadIdx.x;          // grid covers 512*256*64
    int t = idx >> 14;                                  // / (256*64)
    int rem = idx & 16383;
    int b = rem >> 6;
    int i = rem & 63;
    x16[idx] = (_Float16)x[((size_t)b * T_ + t) * I_ + i];
}

// Transposed formulation: G^T = Wcat · hcat^T.
//   A operand = Wcat rows (static, hoisted: 4 gates x 18 K-chunks in AGPRs)
//   B operand = hcat columns == CONTIGUOUS 16B slices of h rows -> direct
//               agent loads, NO LDS staging, no __syncthreads anywhere.
// 512 blocks of 64 threads = 512 independent waves.
//   block = (btile = blk&15, jtile = blk>>4): 16 batches x 16 h-cols, all 4 gates.
// C/D [m89]: col(lane&15) = batch B0+r ; row(q*4+reg) = h-col J0+4q+reg
//   -> lane's 4 cells are 4 CONSECUTIVE h-cols of one batch row: packed 8B store.
// Sync: per-btile 32 sentinels; publish after own vmcnt(0) drain; 32-lane poll.
__launch_bounds__(64, 1)
__global__ void lstm_k(const _Float16* __restrict__ Wcat, const float* __restrict__ bias,
                       const _Float16* __restrict__ x16,
                       _Float16* __restrict__ h0, _Float16* __restrict__ h1,
                       unsigned* __restrict__ snt) {
    const int lane = threadIdx.x;     // 0..63
    const int bt   = blockIdx.x & 15; // batch tile (16 rows)
    const int jt   = blockIdx.x >> 4; // h-col tile 0..31 (16 cols)
    const int B0   = bt * 16;
    const int J0   = jt * 16;
    const int r    = lane & 15;
    const int q    = lane >> 4;

    // --- hoist W A-frags: lane holds A[row=J0+r (gate-row)][k=kk*32+q*8+0..7] ---
    h8 afrag[4][18];
    float biasv[4][4];
#pragma unroll
    for (int g = 0; g < 4; ++g) {
        const _Float16* wr = Wcat + (size_t)(g * H_ + J0 + r) * K_;
#pragma unroll
        for (int kk = 0; kk < 18; ++kk)
            afrag[g][kk] = *(const h8*)(wr + kk * 32 + q * 8);
#pragma unroll
        for (int reg = 0; reg < 4; ++reg)
            biasv[g][reg] = bias[g * H_ + J0 + q * 4 + reg];
    }

    // cell state: lane owns batch B0+r, h-cols J0+4q+{0..3}
    float cc[4] = {0.f, 0.f, 0.f, 0.f};

    unsigned* const mysnt = snt + bt * 32;   // this btile's 32 sentinels (128B)

    // x B-frags for step 0: B[k][batch] = x16[t][B0+r][k-512] (contiguous 16B)
    const u64* const xp64 = (const u64*)x16;
    HU xb[2];
    {
        const u64* xr = xp64 + (size_t)(B0 + r) * 16 + q * 2;   // t = 0
        xb[0].u[0] = xr[0]; xb[0].u[1] = xr[1];
        xb[1].u[0] = xr[8]; xb[1].u[1] = xr[9];
    }

    for (int s = 0; s < T_; ++s) {
        const _Float16* hp = (s & 1) ? h1 : h0;
        _Float16*       hn = (s & 1) ? h0 : h1;

        // ---- h B-frags: direct agent loads (bypass L2), 2x u64 per chunk ----
        // row B0+r = 128 u64; chunk kk at u64 offset kk*8 + q*2
        const u64* hr = (const u64*)hp + (size_t)(B0 + r) * 128 + q * 2;
        HU hb[16];
#pragma unroll
        for (int kk = 0; kk < 16; ++kk) {
            hb[kk].u[0] = __hip_atomic_load(hr + kk * 8,
                                            __ATOMIC_RELAXED, __HIP_MEMORY_SCOPE_AGENT);
            hb[kk].u[1] = __hip_atomic_load(hr + kk * 8 + 1,
                                            __ATOMIC_RELAXED, __HIP_MEMORY_SCOPE_AGENT);
        }

        // ---- MFMA: K = 18 chunks; one B-frag feeds all 4 gate A-tiles ----
        v4f a0 = {0,0,0,0}, a1 = {0,0,0,0}, a2 = {0,0,0,0}, a3 = {0,0,0,0};
#pragma unroll
        for (int kk = 0; kk < 16; ++kk) {
            a0 = __builtin_amdgcn_mfma_f32_16x16x32_f16(afrag[0][kk], hb[kk].v, a0, 0, 0, 0);
            a1 = __builtin_amdgcn_mfma_f32_16x16x32_f16(afrag[1][kk], hb[kk].v, a1, 0, 0, 0);
            a2 = __builtin_amdgcn_mfma_f32_16x16x32_f16(afrag[2][kk], hb[kk].v, a2, 0, 0, 0);
            a3 = __builtin_amdgcn_mfma_f32_16x16x32_f16(afrag[3][kk], hb[kk].v, a3, 0, 0, 0);
        }
#pragma unroll
        for (int c = 0; c < 2; ++c) {
            a0 = __builtin_amdgcn_mfma_f32_16x16x32_f16(afrag[0][16 + c], xb[c].v, a0, 0, 0, 0);
            a1 = __builtin_amdgcn_mfma_f32_16x16x32_f16(afrag[1][16 + c], xb[c].v, a1, 0, 0, 0);
            a2 = __builtin_amdgcn_mfma_f32_16x16x32_f16(afrag[2][16 + c], xb[c].v, a2, 0, 0, 0);
            a3 = __builtin_amdgcn_mfma_f32_16x16x32_f16(afrag[3][16 + c], xb[c].v, a3, 0, 0, 0);
        }

        // x prefetch for s+1 (normal loads; overlap cell + drain)
        if (s + 1 < T_) {
            const u64* xr = xp64 + ((size_t)(s + 1) * B_ + B0 + r) * 16 + q * 2;
            xb[0].u[0] = xr[0]; xb[0].u[1] = xr[1];
            xb[1].u[0] = xr[8]; xb[1].u[1] = xr[9];
        }

        // ---- LSTM cell in registers; single packed 8B h' store ----
        Pack4 pk;
#pragma unroll
        for (int reg = 0; reg < 4; ++reg) {
            float iv = sigf  (a0[reg] + biasv[0][reg]);
            float fv = sigf  (a1[reg] + biasv[1][reg]);
            float gv = tanhf_(a2[reg] + biasv[2][reg]);
            float ov = sigf  (a3[reg] + biasv[3][reg]);
            cc[reg] = fv * cc[reg] + iv * gv;
            pk.f[reg] = (_Float16)(ov * tanhf_(cc[reg]));
        }
        __hip_atomic_store((u64*)(hn + (size_t)(B0 + r) * H_ + J0 + q * 4),
                           pk.u, __ATOMIC_RELAXED, __HIP_MEMORY_SCOPE_AGENT);

        // ---- drain own stores, publish sentinel (no RMW) ----
        asm volatile("s_waitcnt vmcnt(0)" ::: "memory");
        if (lane == 0)
            __hip_atomic_store(mysnt + jt, (unsigned)(s + 1),
                               __ATOMIC_RELAXED, __HIP_MEMORY_SCOPE_AGENT);

        // ---- wait for all 32 producers of this btile (32-lane parallel poll) ----
        {
            const unsigned tgt = (unsigned)(s + 1);
            int guard = 0, done = 0;
            do {
                unsigned v = __hip_atomic_load(mysnt + (lane & 31),
                                               __ATOMIC_RELAXED, __HIP_MEMORY_SCOPE_AGENT);
                done = __all((int)(v >= tgt));
                if (!done) __builtin_amdgcn_s_sleep(1);
            } while (!done && ++guard < (1 << 17));   // anti-hang: fail loud
        }
    }
}

__global__ void fc_k(const _Float16* __restrict__ hlast, const float* __restrict__ Wfc,
                     const float* __restrict__ bfc, float* __restrict__ out) {
    int b = blockIdx.x;
    int lane = threadIdx.x;   // 64 threads
    // h was written with device-scope stores (bypassing L2) -> read device-scope
    const u64* hp64 = (const u64*)(hlast + (size_t)b * H_);
    union { _Float16 f[4]; u64 u; } p0, p1;
    p0.u = __hip_atomic_load(hp64 + lane * 2,     __ATOMIC_RELAXED, __HIP_MEMORY_SCOPE_AGENT);
    p1.u = __hip_atomic_load(hp64 + lane * 2 + 1, __ATOMIC_RELAXED, __HIP_MEMORY_SCOPE_AGENT);
    float sum = 0.f;
#pragma unroll
    for (int j = 0; j < 4; ++j) sum += (float)p0.f[j] * Wfc[lane * 8 + j];
#pragma unroll
    for (int j = 0; j < 4; ++j) sum += (float)p1.f[j] * Wfc[lane * 8 + 4 + j];
    for (int off = 32; off; off >>= 1) sum += __shfl_down(sum, off);
    if (lane == 0) out[b] = sum + bfc[0];
}

extern "C" void kernel_launch(void* const* d_in, const int* in_sizes, int n_in,
                              void* d_out, int out_size, void* d_ws, size_t ws_size,
                              hipStream_t stream) {
    (void)in_sizes; (void)n_in; (void)out_size; (void)ws_size;
    const float* x   = (const float*)d_in[0];
    const float* Wih = (const float*)d_in[1];
    const float* Whh = (const float*)d_in[2];
    const float* bih = (const float*)d_in[3];
    const float* bhh = (const float*)d_in[4];
    const float* Wfc = (const float*)d_in[5];
    const float* bfc = (const float*)d_in[6];
    float* out = (float*)d_out;

    char* ws = (char*)d_ws;
    _Float16* Wcat = (_Float16*)(ws + OFF_WCAT);
    float*    biasf = (float*)(ws + OFF_BIAS);
    _Float16* x16   = (_Float16*)(ws + OFF_X16);
    _Float16* h0b   = (_Float16*)(ws + OFF_H0);
    _Float16* h1b   = (_Float16*)(ws + OFF_H1);
    unsigned* sntb  = (unsigned*)(ws + OFF_SNT);

    hipLaunchKernelGGL(prep_w, dim3((2048 * 512) / 256), dim3(256), 0, stream,
                       Wih, Whh, bih, bhh, Wcat, biasf, h0b, sntb);
    hipLaunchKernelGGL(prep_x, dim3((512 * 256 * 64) / 256), dim3(256), 0, stream, x, x16);
    hipLaunchKernelGGL(lstm_k, dim3(512), dim3(64), 0, stream,
                       Wcat, biasf, x16, h0b, h1b, sntb);
    // T=512 even: last write (s=511, odd) went to buffer 0
    hipLaunchKernelGGL(fc_k, dim3(256), dim3(64), 0, stream, h0b, Wfc, bfc, out);
}

// Round 4
// 3062.547 us; speedup vs baseline: 1.0131x; 1.0131x over previous
//
#include <hip/hip_runtime.h>

typedef _Float16 h8 __attribute__((ext_vector_type(8)));
typedef float v4f __attribute__((ext_vector_type(4)));
typedef unsigned long long u64;

#define B_  256
#define T_  512
#define I_  64
#define H_  512

// workspace layout (bytes)
#define OFF_W16   0                                   // [2048][512] f16
#define OFF_WIH   (OFF_W16 + 2048*512*2)              // [2048][64]  f16
#define OFF_BIAS  (OFF_WIH + 2048*64*2)               // [2048]      f32 (b_ih+b_hh)
#define OFF_X16   (OFF_BIAS + 2048*4)                 // [512][256][64] f16 (transposed)
#define OFF_H0    (OFF_X16 + 512*256*64*2)            // [256][512] f16
#define OFF_H1    (OFF_H0 + 256*512*2)                // [256][512] f16
#define OFF_SNT   (OFF_H1 + 256*512*2)                // sentinels [8 bg][16 cg][4 wave] u32

__device__ __forceinline__ float sigf(float x) {
    float e = __builtin_amdgcn_exp2f(-1.442695041f * x);
    return __builtin_amdgcn_rcpf(1.f + e);
}
__device__ __forceinline__ float tanhf_(float x) {
    float e = __builtin_amdgcn_exp2f(2.885390082f * x);  // exp(2x)
    return 1.f - 2.f * __builtin_amdgcn_rcpf(e + 1.f);
}

union Pack4 { _Float16 f[4]; u64 u; };

__global__ void prep_w(const float* __restrict__ Wih, const float* __restrict__ Whh,
                       const float* __restrict__ bih, const float* __restrict__ bhh,
                       _Float16* __restrict__ W16, _Float16* __restrict__ Wih16,
                       float* __restrict__ bias, _Float16* __restrict__ h0,
                       unsigned* __restrict__ snt) {
    int idx = blockIdx.x * 256 + threadIdx.x;          // grid covers 2048*512
    W16[idx] = (_Float16)Whh[idx];
    if (idx < 2048 * 64)  Wih16[idx] = (_Float16)Wih[idx];
    if (idx < 2048)       bias[idx] = bih[idx] + bhh[idx];
    // h0 zeros + sentinels must be visible at the IF$ coherence point
    if (idx < 32768)
        __hip_atomic_store((u64*)h0 + idx, 0ull,
                           __ATOMIC_RELAXED, __HIP_MEMORY_SCOPE_AGENT);
    if (idx < 512)
        __hip_atomic_store(snt + idx, 0u, __ATOMIC_RELAXED, __HIP_MEMORY_SCOPE_AGENT);
}

__global__ void prep_x(const float* __restrict__ x, _Float16* __restrict__ x16) {
    int idx = blockIdx.x * 256 + threadIdx.x;          // grid covers 512*256*64
    int t = idx >> 14;                                  // / (256*64)
    int rem = idx & 16383;
    int b = rem >> 6;
    int i = rem & 63;
    x16[idx] = (_Float16)x[((size_t)b * T_ + t) * I_ + i];
}

// 128 wgs: 8 batch-groups x 16 col-groups. wg owns 32 batch rows x 32 h-cols
// (=128 gate-cols). Wave w handles gate g=w (both 16-col tiles, both m halves).
// Surgical deltas vs the 1497us baseline:
//  (1) S staging: [32][128] f32, 16B-unit XOR swizzle (unit ^= row&7).
//      Old [32][132] phase-C reads were 8-way bank conflicts; now phase C is
//      4x ds_read_b128, bank-balanced; writes 2-way (free).
//  (2) Publish: per-WAVE sentinel store after own vmcnt(0) drain (64 words/bg)
//      instead of 16 serialized agent-scope fetch_adds on one line; poll is
//      64-lane parallel. Drops one __syncthreads (3/step, not 4).
__launch_bounds__(256, 1)
__global__ void lstm_k(const _Float16* __restrict__ W16, const _Float16* __restrict__ Wih16,
                       const float* __restrict__ bias, const _Float16* __restrict__ x16,
                       _Float16* __restrict__ h0, _Float16* __restrict__ h1,
                       unsigned* __restrict__ snt) {
    __shared__ _Float16 Als[18][33][40];          // 47520 B, A operand chunk-major
    __shared__ __align__(16) char Sb[32 * 512];   // 16384 B, S[32][128] f32 swizzled

    const int tid  = threadIdx.x;
    const int lane = tid & 63;
    const int wave = tid >> 6;        // == gate g (0..3)
    const int bg = blockIdx.x & 7;    // batch group
    const int cg = blockIdx.x >> 3;   // column group 0..15
    const int B0 = bg * 32;
    const int J0 = cg * 32;           // h-column base
    const int r  = lane & 15;
    const int q  = lane >> 4;

    // --- hoist weight B-fragments (persist across all 512 steps) ---
    h8 bfrag[2][18];
    float biasv[2];
#pragma unroll
    for (int t = 0; t < 2; ++t) {
        const int wrow = wave * H_ + J0 + t * 16 + r;   // gate-col index
#pragma unroll
        for (int kk = 0; kk < 16; ++kk)
            bfrag[t][kk] = *(const h8*)(W16 + (size_t)wrow * H_ + kk * 32 + q * 8);
#pragma unroll
        for (int kk = 16; kk < 18; ++kk)
            bfrag[t][kk] = *(const h8*)(Wih16 + (size_t)wrow * I_ + (kk - 16) * 32 + q * 8);
        biasv[t] = bias[wrow];
    }

    // phase-C ownership: thread -> (row er, cols ec..ec+3); c stays in VGPRs
    const int er = tid >> 3;
    const int ec = (tid & 7) * 4;
    float c[4] = {0.f, 0.f, 0.f, 0.f};

    // S write byte-addrs: tile t (col half t*16), reg -> addr (rows 0..15; +8192
    // for rows 16..31). phys = row*512 + ((u ^ (row&7))<<4) + (col&3)*4,
    // u = wave*8 + t*4 + (r>>2)  (XOR flips low 3 bits only -> stays in block).
    int wba[2][4];
#pragma unroll
    for (int t = 0; t < 2; ++t)
#pragma unroll
        for (int reg = 0; reg < 4; ++reg) {
            int row = q * 4 + reg;
            int u   = wave * 8 + t * 4 + (r >> 2);
            wba[t][reg] = row * 512 + (((u ^ (row & 7)) << 4) | ((r & 3) << 2));
        }
    // S read base: unit low3 = tid&7, row = er; gate g at +g*128
    const int rbase = er * 512 + (((tid & 7) ^ (er & 7)) << 4);

    unsigned* const mysnt = snt + bg * 64;  // 64 per-wave sentinels per bg

    // x prefetch for step 0
    const int xrow = tid >> 3, xs8 = tid & 7;
    h8 xv = *(const h8*)(x16 + ((size_t)B0 + xrow) * I_ + xs8 * 8);

    for (int s = 0; s < T_; ++s) {
        const _Float16* hp = (s & 1) ? h1 : h0;
        _Float16*       hn = (s & 1) ? h0 : h1;

        // ---- phase A: h (device-scope, bypasses L1/L2) + x into LDS ----
        {
            const u64* hp64 = (const u64*)(hp + (size_t)B0 * H_);
            u64 hv[16];
#pragma unroll
            for (int it = 0; it < 16; ++it)
                hv[it] = __hip_atomic_load(hp64 + tid + 256 * it,
                                           __ATOMIC_RELAXED, __HIP_MEMORY_SCOPE_AGENT);
            *(h8*)&Als[16 + (xs8 >> 2)][xrow][(xs8 & 3) * 8] = xv;
#pragma unroll
            for (int it = 0; it < 16; ++it) {
                int n = tid + 256 * it;    // 8B unit: row n>>7, chunk (n&127)>>3, off (n&7)*4
                *(u64*)&Als[(n & 127) >> 3][n >> 7][(n & 7) * 4] = hv[it];
            }
        }
        __syncthreads();

        // ---- phase B: MFMA, K = 18 chunks of 32; 4 acc chains/wave ----
        v4f a00 = {0,0,0,0}, a01 = {0,0,0,0}, a10 = {0,0,0,0}, a11 = {0,0,0,0};
#pragma unroll
        for (int kk = 0; kk < 18; ++kk) {
            h8 am0 = *(const h8*)&Als[kk][r][q * 8];
            h8 am1 = *(const h8*)&Als[kk][16 + r][q * 8];
            a00 = __builtin_amdgcn_mfma_f32_16x16x32_f16(am0, bfrag[0][kk], a00, 0, 0, 0);
            a01 = __builtin_amdgcn_mfma_f32_16x16x32_f16(am1, bfrag[0][kk], a01, 0, 0, 0);
            a10 = __builtin_amdgcn_mfma_f32_16x16x32_f16(am0, bfrag[1][kk], a10, 0, 0, 0);
            a11 = __builtin_amdgcn_mfma_f32_16x16x32_f16(am1, bfrag[1][kk], a11, 0, 0, 0);
        }
        // C/D: col = lane&15 (gate-col), row = q*4+reg (batch)  [m89-verified]
#pragma unroll
        for (int reg = 0; reg < 4; ++reg) {
            *(float*)(Sb + wba[0][reg])        = a00[reg] + biasv[0];
            *(float*)(Sb + wba[0][reg] + 8192) = a01[reg] + biasv[0];
            *(float*)(Sb + wba[1][reg])        = a10[reg] + biasv[1];
            *(float*)(Sb + wba[1][reg] + 8192) = a11[reg] + biasv[1];
        }
        __syncthreads();

        // ---- phase C: LSTM cell; thread owns (er, ec..ec+3); b128 gate reads ----
        {
            v4f vi = *(const v4f*)(Sb + rbase);          // gate i (cols 0..31)
            v4f vf = *(const v4f*)(Sb + rbase + 128);    // gate f
            v4f vg = *(const v4f*)(Sb + rbase + 256);    // gate g
            v4f vo = *(const v4f*)(Sb + rbase + 384);    // gate o
            Pack4 pk;
#pragma unroll
            for (int j = 0; j < 4; ++j) {
                float iv = sigf  (vi[j]);
                float fv = sigf  (vf[j]);
                float gv = tanhf_(vg[j]);
                float ov = sigf  (vo[j]);
                c[j] = fv * c[j] + iv * gv;
                pk.f[j] = (_Float16)(ov * tanhf_(c[j]));
            }
            __hip_atomic_store(
                (u64*)(hn + ((size_t)B0 + er) * H_ + J0 + ec),
                pk.u, __ATOMIC_RELAXED, __HIP_MEMORY_SCOPE_AGENT);
        }

        // ---- per-wave release: drain own stores, publish sentinel (no RMW) ----
        asm volatile("s_waitcnt vmcnt(0)" ::: "memory");
        if (lane == 0)
            __hip_atomic_store(mysnt + cg * 4 + wave, (unsigned)(s + 1),
                               __ATOMIC_RELAXED, __HIP_MEMORY_SCOPE_AGENT);
        // x prefetch for s+1 overlaps the poll
        if (s + 1 < T_)
            xv = *(const h8*)(x16 + (((size_t)(s + 1)) * B_ + B0 + xrow) * I_ + xs8 * 8);

        // ---- wait all 64 producer-waves of this bg (64-lane parallel poll) ----
        {
            const unsigned tgt = (unsigned)(s + 1);
            int guard = 0, done = 0;
            do {
                unsigned v = __hip_atomic_load(mysnt + lane,
                                               __ATOMIC_RELAXED, __HIP_MEMORY_SCOPE_AGENT);
                done = __all((int)(v >= tgt));
                if (!done) __builtin_amdgcn_s_sleep(1);
            } while (!done && ++guard < (1 << 17));   // anti-hang: fail loud
        }
        __syncthreads();
    }
}

__global__ void fc_k(const _Float16* __restrict__ hlast, const float* __restrict__ Wfc,
                     const float* __restrict__ bfc, float* __restrict__ out) {
    int b = blockIdx.x;
    int lane = threadIdx.x;   // 64 threads
    // h was written with device-scope stores (bypassing L2) -> read device-scope
    const u64* hp64 = (const u64*)(hlast + (size_t)b * H_);
    Pack4 p0, p1;
    p0.u = __hip_atomic_load(hp64 + lane * 2,     __ATOMIC_RELAXED, __HIP_MEMORY_SCOPE_AGENT);
    p1.u = __hip_atomic_load(hp64 + lane * 2 + 1, __ATOMIC_RELAXED, __HIP_MEMORY_SCOPE_AGENT);
    float sum = 0.f;
#pragma unroll
    for (int j = 0; j < 4; ++j) sum += (float)p0.f[j] * Wfc[lane * 8 + j];
#pragma unroll
    for (int j = 0; j < 4; ++j) sum += (float)p1.f[j] * Wfc[lane * 8 + 4 + j];
    for (int off = 32; off; off >>= 1) sum += __shfl_down(sum, off);
    if (lane == 0) out[b] = sum + bfc[0];
}

extern "C" void kernel_launch(void* const* d_in, const int* in_sizes, int n_in,
                              void* d_out, int out_size, void* d_ws, size_t ws_size,
                              hipStream_t stream) {
    (void)in_sizes; (void)n_in; (void)out_size; (void)ws_size;
    const float* x   = (const float*)d_in[0];
    const float* Wih = (const float*)d_in[1];
    const float* Whh = (const float*)d_in[2];
    const float* bih = (const float*)d_in[3];
    const float* bhh = (const float*)d_in[4];
    const float* Wfc = (const float*)d_in[5];
    const float* bfc = (const float*)d_in[6];
    float* out = (float*)d_out;

    char* ws = (char*)d_ws;
    _Float16* W16   = (_Float16*)(ws + OFF_W16);
    _Float16* Wih16 = (_Float16*)(ws + OFF_WIH);
    float*    biasf = (float*)(ws + OFF_BIAS);
    _Float16* x16   = (_Float16*)(ws + OFF_X16);
    _Float16* h0b   = (_Float16*)(ws + OFF_H0);
    _Float16* h1b   = (_Float16*)(ws + OFF_H1);
    unsigned* sntb  = (unsigned*)(ws + OFF_SNT);

    hipLaunchKernelGGL(prep_w, dim3((2048 * 512) / 256), dim3(256), 0, stream,
                       Wih, Whh, bih, bhh, W16, Wih16, biasf, h0b, sntb);
    hipLaunchKernelGGL(prep_x, dim3((512 * 256 * 64) / 256), dim3(256), 0, stream, x, x16);
    hipLaunchKernelGGL(lstm_k, dim3(128), dim3(256), 0, stream,
                       W16, Wih16, biasf, x16, h0b, h1b, sntb);
    // T=512 even: last write went to buffer 0
    hipLaunchKernelGGL(fc_k, dim3(256), dim3(64), 0, stream, h0b, Wfc, bfc, out);
}

// Round 5
// 1525.740 us; speedup vs baseline: 2.0335x; 2.0073x over previous
//
#include <hip/hip_runtime.h>

typedef _Float16 h8 __attribute__((ext_vector_type(8)));
typedef float v4f __attribute__((ext_vector_type(4)));
typedef unsigned long long u64;

#define B_  256
#define T_  512
#define I_  64
#define H_  512

// workspace layout (bytes)
#define OFF_W16   0                                   // [2048][512] f16
#define OFF_WIH   (OFF_W16 + 2048*512*2)              // [2048][64]  f16
#define OFF_BIAS  (OFF_WIH + 2048*64*2)               // [2048]      f32 (b_ih+b_hh)
#define OFF_X16   (OFF_BIAS + 2048*4)                 // [512][256][64] f16 (transposed)
#define OFF_H0    (OFF_X16 + 512*256*64*2)            // [256][512] f16
#define OFF_H1    (OFF_H0 + 256*512*2)                // [256][512] f16
#define OFF_CTR   (OFF_H1 + 256*512*2)                // 8 counters, 64B apart

// LDS A-chunk stride: 2048 + 16 so that chunk index contributes 4*kk (mod 32)
// to the bank -> staging writes land exactly 4 dwords/bank (perfectly balanced)
#define CS_ 2064

__device__ __forceinline__ float sigf(float x) {
    float e = __builtin_amdgcn_exp2f(-1.442695041f * x);
    return __builtin_amdgcn_rcpf(1.f + e);
}
__device__ __forceinline__ float tanhf_(float x) {
    float e = __builtin_amdgcn_exp2f(2.885390082f * x);  // exp(2x)
    return 1.f - 2.f * __builtin_amdgcn_rcpf(e + 1.f);
}

union Pack4 { _Float16 f[4]; u64 u; };

__global__ void prep_w(const float* __restrict__ Wih, const float* __restrict__ Whh,
                       const float* __restrict__ bih, const float* __restrict__ bhh,
                       _Float16* __restrict__ W16, _Float16* __restrict__ Wih16,
                       float* __restrict__ bias, _Float16* __restrict__ h0,
                       unsigned* __restrict__ ctr) {
    int idx = blockIdx.x * 256 + threadIdx.x;          // grid covers 2048*512
    W16[idx] = (_Float16)Whh[idx];
    if (idx < 2048 * 64)  Wih16[idx] = (_Float16)Wih[idx];
    if (idx < 2048)       bias[idx] = bih[idx] + bhh[idx];
    // h0 zeros must be visible at the IF$ coherence point (lstm_k reads them
    // with device-scope loads that bypass L2) -> device-scope atomic stores.
    if (idx < 32768)
        __hip_atomic_store((u64*)h0 + idx, 0ull,
                           __ATOMIC_RELAXED, __HIP_MEMORY_SCOPE_AGENT);
    if (idx < 128)
        __hip_atomic_store(ctr + idx, 0u, __ATOMIC_RELAXED, __HIP_MEMORY_SCOPE_AGENT);
}

__global__ void prep_x(const float* __restrict__ x, _Float16* __restrict__ x16) {
    int idx = blockIdx.x * 256 + threadIdx.x;          // grid covers 512*256*64
    int t = idx >> 14;                                  // / (256*64)
    int rem = idx & 16383;
    int b = rem >> 6;
    int i = rem & 63;
    x16[idx] = (_Float16)x[((size_t)b * T_ + t) * I_ + i];
}

// 128 wgs: 8 batch-groups x 16 col-groups. wg owns 32 batch rows x 32 h-cols
// (=128 gate-cols). Wave w handles gate g=w (both 16-col tiles, both m halves).
// EXACT 1497us-baseline protocol (counter RMW publish, tid==0 single poll,
// 4 barriers). Only the two LDS layouts changed (both bank-balance verified):
//  (1) A staging: flat, chunk stride 2064B, 16B-slot XOR (sub ^= row&3).
//      Old [18][33][40] scatter was a 4-way conflict on all 16 writes
//      (928 conflict-cy/step/wg = the measured 6.1e7 residual). New layout:
//      writes exactly 4 dwords/bank, b128 reads exactly 8 dwords/bank.
//  (2) S: [32][128] f32 swizzled (r4-verified); phase C = 4x ds_read_b128.
__launch_bounds__(256, 1)
__global__ void lstm_k(const _Float16* __restrict__ W16, const _Float16* __restrict__ Wih16,
                       const float* __restrict__ bias, const _Float16* __restrict__ x16,
                       _Float16* __restrict__ h0, _Float16* __restrict__ h1,
                       unsigned* __restrict__ ctr) {
    __shared__ __align__(16) char Ab[18 * CS_];   // 37152 B, A operand swizzled
    __shared__ __align__(16) char Sb[32 * 512];   // 16384 B, S[32][128] f32 swizzled

    const int tid  = threadIdx.x;
    const int lane = tid & 63;
    const int wave = tid >> 6;        // == gate g (0..3)
    const int bg = blockIdx.x & 7;    // batch group
    const int cg = blockIdx.x >> 3;   // column group 0..15
    const int B0 = bg * 32;
    const int J0 = cg * 32;           // h-column base
    const int r  = lane & 15;
    const int q  = lane >> 4;

    // --- hoist weight B-fragments (persist across all 512 steps) ---
    h8 bfrag[2][18];
    float biasv[2];
#pragma unroll
    for (int t = 0; t < 2; ++t) {
        const int wrow = wave * H_ + J0 + t * 16 + r;   // gate-col index
#pragma unroll
        for (int kk = 0; kk < 16; ++kk)
            bfrag[t][kk] = *(const h8*)(W16 + (size_t)wrow * H_ + kk * 32 + q * 8);
#pragma unroll
        for (int kk = 16; kk < 18; ++kk)
            bfrag[t][kk] = *(const h8*)(Wih16 + (size_t)wrow * I_ + (kk - 16) * 32 + q * 8);
        biasv[t] = bias[wrow];
    }

    // phase-A write constants: unit u = tid + 256*it ->
    //   row = u>>7 = (tid>>7) + 2*it, kk = (u>>3)&15, u8 = tid&7
    //   byte = kk*CS_ + row*64 + (((u8>>1) ^ (row&3))<<4) + (u8&1)*8
    const int kk_w  = (tid >> 3) & 15;
    const int u8s   = (tid & 7) >> 1;
    const int wbase = kk_w * CS_ + ((tid & 1) << 3);
    const int rw0   = tid >> 7;
    // x write: xrow = tid>>3 (0..31), xs8 = tid&7 -> chunk 16+(xs8>>2), sub xs8&3
    const int xrow = tid >> 3, xs8 = tid & 7;
    const int xwb  = (16 + (xs8 >> 2)) * CS_ + xrow * 64
                   + (((xs8 & 3) ^ (xrow & 3)) << 4);
    // phase-B read base for row r (row 16+r is +1024; (16+r)&3 == r&3)
    const int rb0 = r * 64 + ((q ^ (r & 3)) << 4);

    // phase-C ownership: thread -> (row er, cols ec..ec+3); c stays in VGPRs
    const int er = tid >> 3;
    const int ec = (tid & 7) * 4;
    float c[4] = {0.f, 0.f, 0.f, 0.f};

    // S write byte-addrs (r4-verified): phys = row*512 + ((u ^ (row&7))<<4)
    //   + (col&3)*4, u = wave*8 + t*4 + (r>>2); rows 16..31 at +8192.
    int wba[2][4];
#pragma unroll
    for (int t = 0; t < 2; ++t)
#pragma unroll
        for (int reg = 0; reg < 4; ++reg) {
            int row = q * 4 + reg;
            int u   = wave * 8 + t * 4 + (r >> 2);
            wba[t][reg] = row * 512 + (((u ^ (row & 7)) << 4) | ((r & 3) << 2));
        }
    // S read base: unit low3 = tid&7, row = er; gate g at +g*128
    const int rbase = er * 512 + (((tid & 7) ^ (er & 7)) << 4);

    unsigned* myctr = ctr + bg * 16;  // 64B-separated per-group counters

    // x prefetch for step 0
    h8 xv = *(const h8*)(x16 + ((size_t)B0 + xrow) * I_ + xs8 * 8);

    for (int s = 0; s < T_; ++s) {
        const _Float16* hp = (s & 1) ? h1 : h0;
        _Float16*       hn = (s & 1) ? h0 : h1;

        // ---- phase A: h (device-scope, bypasses L1/L2) + x into LDS ----
        {
            const u64* hp64 = (const u64*)(hp + (size_t)B0 * H_);
            u64 hv[16];
#pragma unroll
            for (int it = 0; it < 16; ++it)
                hv[it] = __hip_atomic_load(hp64 + tid + 256 * it,
                                           __ATOMIC_RELAXED, __HIP_MEMORY_SCOPE_AGENT);
            *(h8*)(Ab + xwb) = xv;
#pragma unroll
            for (int it = 0; it < 16; ++it) {
                int row = rw0 + 2 * it;
                *(u64*)(Ab + wbase + row * 64 + ((u8s ^ (row & 3)) << 4)) = hv[it];
            }
        }
        __syncthreads();

        // ---- phase B: MFMA, K = 18 chunks of 32; 4 acc chains/wave ----
        v4f a00 = {0,0,0,0}, a01 = {0,0,0,0}, a10 = {0,0,0,0}, a11 = {0,0,0,0};
#pragma unroll
        for (int kk = 0; kk < 18; ++kk) {
            h8 am0 = *(const h8*)(Ab + kk * CS_ + rb0);          // row r
            h8 am1 = *(const h8*)(Ab + kk * CS_ + rb0 + 1024);   // row 16+r
            a00 = __builtin_amdgcn_mfma_f32_16x16x32_f16(am0, bfrag[0][kk], a00, 0, 0, 0);
            a01 = __builtin_amdgcn_mfma_f32_16x16x32_f16(am1, bfrag[0][kk], a01, 0, 0, 0);
            a10 = __builtin_amdgcn_mfma_f32_16x16x32_f16(am0, bfrag[1][kk], a10, 0, 0, 0);
            a11 = __builtin_amdgcn_mfma_f32_16x16x32_f16(am1, bfrag[1][kk], a11, 0, 0, 0);
        }
        // C/D: col = lane&15 (gate-col), row = q*4+reg (batch)  [m89-verified]
#pragma unroll
        for (int reg = 0; reg < 4; ++reg) {
            *(float*)(Sb + wba[0][reg])        = a00[reg] + biasv[0];
            *(float*)(Sb + wba[0][reg] + 8192) = a01[reg] + biasv[0];
            *(float*)(Sb + wba[1][reg])        = a10[reg] + biasv[1];
            *(float*)(Sb + wba[1][reg] + 8192) = a11[reg] + biasv[1];
        }
        __syncthreads();

        // ---- phase C: LSTM cell; thread owns (er, ec..ec+3); b128 gate reads ----
        {
            v4f vi = *(const v4f*)(Sb + rbase);          // gate i (cols 0..31)
            v4f vf = *(const v4f*)(Sb + rbase + 128);    // gate f
            v4f vg = *(const v4f*)(Sb + rbase + 256);    // gate g
            v4f vo = *(const v4f*)(Sb + rbase + 384);    // gate o
            Pack4 pk;
#pragma unroll
            for (int j = 0; j < 4; ++j) {
                float iv = sigf  (vi[j]);
                float fv = sigf  (vf[j]);
                float gv = tanhf_(vg[j]);
                float ov = sigf  (vo[j]);
                c[j] = fv * c[j] + iv * gv;
                pk.f[j] = (_Float16)(ov * tanhf_(c[j]));
            }
            __hip_atomic_store(
                (u64*)(hn + ((size_t)B0 + er) * H_ + J0 + ec),
                pk.u, __ATOMIC_RELAXED, __HIP_MEMORY_SCOPE_AGENT);
        }
        __syncthreads();   // implicit vmcnt(0): all lanes' h stores ack'd at IF$

        // ---- per-group barrier: relaxed device-scope counter, no L2 flush ----
        if (tid == 0)
            __hip_atomic_fetch_add(myctr, 1u, __ATOMIC_RELAXED, __HIP_MEMORY_SCOPE_AGENT);
        // x prefetch for s+1 overlaps the poll
        if (s + 1 < T_)
            xv = *(const h8*)(x16 + (((size_t)(s + 1)) * B_ + B0 + xrow) * I_ + xs8 * 8);
        if (tid == 0) {
            const unsigned target = 16u * (unsigned)(s + 1);
            int guard = 0;
            while (__hip_atomic_load(myctr, __ATOMIC_RELAXED, __HIP_MEMORY_SCOPE_AGENT) < target) {
                __builtin_amdgcn_s_sleep(1);
                if (++guard > (1 << 17)) break;   // anti-hang: fail loud, not silent
            }
        }
        __syncthreads();
    }
}

__global__ void fc_k(const _Float16* __restrict__ hlast, const float* __restrict__ Wfc,
                     const float* __restrict__ bfc, float* __restrict__ out) {
    int b = blockIdx.x;
    int lane = threadIdx.x;   // 64 threads
    // h was written with device-scope stores (bypassing L2) -> read device-scope
    const u64* hp64 = (const u64*)(hlast + (size_t)b * H_);
    Pack4 p0, p1;
    p0.u = __hip_atomic_load(hp64 + lane * 2,     __ATOMIC_RELAXED, __HIP_MEMORY_SCOPE_AGENT);
    p1.u = __hip_atomic_load(hp64 + lane * 2 + 1, __ATOMIC_RELAXED, __HIP_MEMORY_SCOPE_AGENT);
    float sum = 0.f;
#pragma unroll
    for (int j = 0; j < 4; ++j) sum += (float)p0.f[j] * Wfc[lane * 8 + j];
#pragma unroll
    for (int j = 0; j < 4; ++j) sum += (float)p1.f[j] * Wfc[lane * 8 + 4 + j];
    for (int off = 32; off; off >>= 1) sum += __shfl_down(sum, off);
    if (lane == 0) out[b] = sum + bfc[0];
}

extern "C" void kernel_launch(void* const* d_in, const int* in_sizes, int n_in,
                              void* d_out, int out_size, void* d_ws, size_t ws_size,
                              hipStream_t stream) {
    (void)in_sizes; (void)n_in; (void)out_size; (void)ws_size;
    const float* x   = (const float*)d_in[0];
    const float* Wih = (const float*)d_in[1];
    const float* Whh = (const float*)d_in[2];
    const float* bih = (const float*)d_in[3];
    const float* bhh = (const float*)d_in[4];
    const float* Wfc = (const float*)d_in[5];
    const float* bfc = (const float*)d_in[6];
    float* out = (float*)d_out;

    char* ws = (char*)d_ws;
    _Float16* W16   = (_Float16*)(ws + OFF_W16);
    _Float16* Wih16 = (_Float16*)(ws + OFF_WIH);
    float*    biasf = (float*)(ws + OFF_BIAS);
    _Float16* x16   = (_Float16*)(ws + OFF_X16);
    _Float16* h0b   = (_Float16*)(ws + OFF_H0);
    _Float16* h1b   = (_Float16*)(ws + OFF_H1);
    unsigned* ctrb  = (unsigned*)(ws + OFF_CTR);

    hipLaunchKernelGGL(prep_w, dim3((2048 * 512) / 256), dim3(256), 0, stream,
                       Wih, Whh, bih, bhh, W16, Wih16, biasf, h0b, ctrb);
    hipLaunchKernelGGL(prep_x, dim3((512 * 256 * 64) / 256), dim3(256), 0, stream, x, x16);
    hipLaunchKernelGGL(lstm_k, dim3(128), dim3(256), 0, stream,
                       W16, Wih16, biasf, x16, h0b, h1b, ctrb);
    // T=512 even: last write went to buffer 0
    hipLaunchKernelGGL(fc_k, dim3(256), dim3(64), 0, stream, h0b, Wfc, bfc, out);
}

// Round 6
// 1439.327 us; speedup vs baseline: 2.1556x; 1.0600x over previous
//
#include <hip/hip_runtime.h>

typedef _Float16 h8 __attribute__((ext_vector_type(8)));
typedef float v4f __attribute__((ext_vector_type(4)));
typedef unsigned long long u64;

#define B_  256
#define T_  512
#define I_  64
#define H_  512

// workspace layout (bytes)
#define OFF_W16   0                                   // [2048][512] f16
#define OFF_WIH   (OFF_W16 + 2048*512*2)              // [2048][64]  f16
#define OFF_BIAS  (OFF_WIH + 2048*64*2)               // [2048]      f32 (b_ih+b_hh)
#define OFF_X16   (OFF_BIAS + 2048*4)                 // [512][256][64] f16 (t-major)
#define OFF_H0    (OFF_X16 + 512*256*64*2)            // [256][512] f16
#define OFF_H1    (OFF_H0 + 256*512*2)                // [256][512] f16
#define OFF_CTR   (OFF_H1 + 256*512*2)                // 16 counters, 64B apart

// LDS chunk stride 1040 = 1024+16: kk contributes 4*kk mod 32 to the bank.
// Verified: 8B staging writes = exactly 4 dwords/bank; b128 reads = 8/bank.
#define CS_ 1040

__device__ __forceinline__ float sigf(float x) {
    float e = __builtin_amdgcn_exp2f(-1.442695041f * x);
    return __builtin_amdgcn_rcpf(1.f + e);
}
__device__ __forceinline__ float tanhf_(float x) {
    float e = __builtin_amdgcn_exp2f(2.885390082f * x);  // exp(2x)
    return 1.f - 2.f * __builtin_amdgcn_rcpf(e + 1.f);
}

union Pack4 { _Float16 f[4]; u64 u; };

__global__ void prep_w(const float* __restrict__ Wih, const float* __restrict__ Whh,
                       const float* __restrict__ bih, const float* __restrict__ bhh,
                       _Float16* __restrict__ W16, _Float16* __restrict__ Wih16,
                       float* __restrict__ bias, _Float16* __restrict__ h0,
                       unsigned* __restrict__ ctr) {
    int idx = blockIdx.x * 256 + threadIdx.x;          // grid covers 2048*512
    W16[idx] = (_Float16)Whh[idx];
    if (idx < 2048 * 64)  Wih16[idx] = (_Float16)Wih[idx];
    if (idx < 2048)       bias[idx] = bih[idx] + bhh[idx];
    // h0 zeros must be visible at the IF$ coherence point (lstm_k reads them
    // with device-scope loads that bypass L2) -> device-scope atomic stores.
    if (idx < 32768)
        __hip_atomic_store((u64*)h0 + idx, 0ull,
                           __ATOMIC_RELAXED, __HIP_MEMORY_SCOPE_AGENT);
    if (idx < 256)
        __hip_atomic_store(ctr + idx, 0u, __ATOMIC_RELAXED, __HIP_MEMORY_SCOPE_AGENT);
}

__global__ void prep_x(const float* __restrict__ x, _Float16* __restrict__ x16) {
    int idx = blockIdx.x * 256 + threadIdx.x;          // grid covers 512*256*64
    int t = idx >> 14;                                  // / (256*64)
    int rem = idx & 16383;
    int b = rem >> 6;
    int i = rem & 63;
    x16[idx] = (_Float16)x[((size_t)b * T_ + t) * I_ + i];
}

// 128 wgs: 16 batch-groups x 8 col-groups. wg = 16 batch rows x 64 h-cols.
// Wave wv owns h-cols J0+16wv..+15 for ALL FOUR gates (bfrag[4][16]) ->
// i,f,g,o land in the same lane/reg of 4 accumulators: the LSTM cell runs
// fully in registers (no S staging, no 3rd barrier). x bypasses LDS: per-lane
// direct fragment loads (prefetched 1 step ahead); the 8 x-MFMAs issue while
// the h agent-loads are in flight. Rendezvous: 8 producers per bg (halved),
// EXACT baseline protocol (counter RMW publish, tid==0 single poll).
__launch_bounds__(256, 1)
__global__ void lstm_k(const _Float16* __restrict__ W16, const _Float16* __restrict__ Wih16,
                       const float* __restrict__ bias, const _Float16* __restrict__ x16,
                       _Float16* __restrict__ h0, _Float16* __restrict__ h1,
                       unsigned* __restrict__ ctr) {
    __shared__ __align__(16) char Ab[16 * CS_];   // 16640 B, h-tile staging

    const int tid  = threadIdx.x;
    const int lane = tid & 63;
    const int wv   = tid >> 6;        // wave = h-col sub-block (0..3)
    const int bg   = blockIdx.x & 15; // batch group (16 rows)
    const int cg   = blockIdx.x >> 4; // column group 0..7
    const int B0   = bg * 16;
    const int J0   = cg * 64;         // h-column base
    const int r    = lane & 15;
    const int q    = lane >> 4;

    // --- hoist weights: 4 gates x 16 h-chunks + 2 x-chunks (~290 VGPRs) ---
    h8 bfrag[4][16];
    h8 xbfrag[4][2];
    float biasv[4];
#pragma unroll
    for (int g = 0; g < 4; ++g) {
        const int wrow = g * H_ + J0 + wv * 16 + r;     // gate-col index
#pragma unroll
        for (int kk = 0; kk < 16; ++kk)
            bfrag[g][kk] = *(const h8*)(W16 + (size_t)wrow * H_ + kk * 32 + q * 8);
#pragma unroll
        for (int c = 0; c < 2; ++c)
            xbfrag[g][c] = *(const h8*)(Wih16 + (size_t)wrow * I_ + c * 32 + q * 8);
        biasv[g] = bias[wrow];
    }

    // staging constants: unit u = tid + 256*it -> row = (tid>>7)+2*it,
    // kk = (tid>>3)&15, byte = kk*CS_ + row*64 + (tid&7)*8
    const int wbase = ((tid >> 3) & 15) * CS_ + (tid & 7) * 8;
    const int rw0   = tid >> 7;
    // phase-B read base: chunk kk, row r, bytes q*16..
    const int rb0 = r * 64 + q * 16;

    // cell state: lane owns batch rows B0+4q+reg, h-col J0+16wv+r
    float cc[4] = {0.f, 0.f, 0.f, 0.f};

    unsigned* myctr = ctr + bg * 16;  // 64B-separated per-bg counters

    // x A-frags for step 0: lane (r,q) needs x16[t][B0+r][c*32 + q*8 ..+7]
    const _Float16* xrow0 = x16 + (size_t)(B0 + r) * I_ + q * 8;
    h8 xa0 = *(const h8*)(xrow0);
    h8 xa1 = *(const h8*)(xrow0 + 32);

    for (int s = 0; s < T_; ++s) {
        const _Float16* hp = (s & 1) ? h1 : h0;
        _Float16*       hn = (s & 1) ? h0 : h1;

        // ---- phase A: issue h agent-loads (bypass L1/L2) ----
        u64 hv[8];
        {
            const u64* hp64 = (const u64*)(hp + (size_t)B0 * H_);
#pragma unroll
            for (int it = 0; it < 8; ++it)
                hv[it] = __hip_atomic_load(hp64 + tid + 256 * it,
                                           __ATOMIC_RELAXED, __HIP_MEMORY_SCOPE_AGENT);
        }

        // ---- x-part MFMAs overlap the h-load latency (register-only) ----
        v4f a0 = {0,0,0,0}, a1 = {0,0,0,0}, a2 = {0,0,0,0}, a3 = {0,0,0,0};
        a0 = __builtin_amdgcn_mfma_f32_16x16x32_f16(xa0, xbfrag[0][0], a0, 0, 0, 0);
        a1 = __builtin_amdgcn_mfma_f32_16x16x32_f16(xa0, xbfrag[1][0], a1, 0, 0, 0);
        a2 = __builtin_amdgcn_mfma_f32_16x16x32_f16(xa0, xbfrag[2][0], a2, 0, 0, 0);
        a3 = __builtin_amdgcn_mfma_f32_16x16x32_f16(xa0, xbfrag[3][0], a3, 0, 0, 0);
        a0 = __builtin_amdgcn_mfma_f32_16x16x32_f16(xa1, xbfrag[0][1], a0, 0, 0, 0);
        a1 = __builtin_amdgcn_mfma_f32_16x16x32_f16(xa1, xbfrag[1][1], a1, 0, 0, 0);
        a2 = __builtin_amdgcn_mfma_f32_16x16x32_f16(xa1, xbfrag[2][1], a2, 0, 0, 0);
        a3 = __builtin_amdgcn_mfma_f32_16x16x32_f16(xa1, xbfrag[3][1], a3, 0, 0, 0);

        // ---- stage h into LDS (waits loads), barrier ----
#pragma unroll
        for (int it = 0; it < 8; ++it) {
            int row = rw0 + 2 * it;
            *(u64*)(Ab + wbase + row * 64) = hv[it];
        }
        __syncthreads();

        // ---- phase B: h-part MFMA, 16 chunks; one A-frag feeds 4 gates ----
#pragma unroll
        for (int kk = 0; kk < 16; ++kk) {
            const h8 am = *(const h8*)(Ab + kk * CS_ + rb0);
            a0 = __builtin_amdgcn_mfma_f32_16x16x32_f16(am, bfrag[0][kk], a0, 0, 0, 0);
            a1 = __builtin_amdgcn_mfma_f32_16x16x32_f16(am, bfrag[1][kk], a1, 0, 0, 0);
            a2 = __builtin_amdgcn_mfma_f32_16x16x32_f16(am, bfrag[2][kk], a2, 0, 0, 0);
            a3 = __builtin_amdgcn_mfma_f32_16x16x32_f16(am, bfrag[3][kk], a3, 0, 0, 0);
        }

        // ---- phase C: LSTM cell in registers; h' as 4x2B agent stores ----
        // C/D [m89/r2-verified]: col = lane&15 = h-col r; row = q*4+reg = batch
        {
            unsigned short* hw = (unsigned short*)hn
                               + (size_t)(B0 + q * 4) * H_ + J0 + wv * 16 + r;
#pragma unroll
            for (int reg = 0; reg < 4; ++reg) {
                float iv = sigf  (a0[reg] + biasv[0]);
                float fv = sigf  (a1[reg] + biasv[1]);
                float gv = tanhf_(a2[reg] + biasv[2]);
                float ov = sigf  (a3[reg] + biasv[3]);
                cc[reg] = fv * cc[reg] + iv * gv;
                union { _Float16 f; unsigned short u; } cv;
                cv.f = (_Float16)(ov * tanhf_(cc[reg]));
                __hip_atomic_store(hw + (size_t)reg * H_, cv.u,
                                   __ATOMIC_RELAXED, __HIP_MEMORY_SCOPE_AGENT);
            }
        }
        __syncthreads();   // implicit vmcnt(0): all lanes' h stores ack'd at IF$

        // ---- per-group barrier: relaxed device-scope counter, no L2 flush ----
        if (tid == 0)
            __hip_atomic_fetch_add(myctr, 1u, __ATOMIC_RELAXED, __HIP_MEMORY_SCOPE_AGENT);
        // x A-frag prefetch for s+1 overlaps the poll
        if (s + 1 < T_) {
            const _Float16* xr = x16 + ((size_t)(s + 1) * B_ + B0 + r) * I_ + q * 8;
            xa0 = *(const h8*)(xr);
            xa1 = *(const h8*)(xr + 32);
        }
        if (tid == 0) {
            const unsigned target = 8u * (unsigned)(s + 1);
            int guard = 0;
            while (__hip_atomic_load(myctr, __ATOMIC_RELAXED, __HIP_MEMORY_SCOPE_AGENT) < target) {
                __builtin_amdgcn_s_sleep(1);
                if (++guard > (1 << 17)) break;   // anti-hang: fail loud, not silent
            }
        }
        __syncthreads();
    }
}

__global__ void fc_k(const _Float16* __restrict__ hlast, const float* __restrict__ Wfc,
                     const float* __restrict__ bfc, float* __restrict__ out) {
    int b = blockIdx.x;
    int lane = threadIdx.x;   // 64 threads
    // h was written with device-scope stores (bypassing L2) -> read device-scope
    const u64* hp64 = (const u64*)(hlast + (size_t)b * H_);
    Pack4 p0, p1;
    p0.u = __hip_atomic_load(hp64 + lane * 2,     __ATOMIC_RELAXED, __HIP_MEMORY_SCOPE_AGENT);
    p1.u = __hip_atomic_load(hp64 + lane * 2 + 1, __ATOMIC_RELAXED, __HIP_MEMORY_SCOPE_AGENT);
    float sum = 0.f;
#pragma unroll
    for (int j = 0; j < 4; ++j) sum += (float)p0.f[j] * Wfc[lane * 8 + j];
#pragma unroll
    for (int j = 0; j < 4; ++j) sum += (float)p1.f[j] * Wfc[lane * 8 + 4 + j];
    for (int off = 32; off; off >>= 1) sum += __shfl_down(sum, off);
    if (lane == 0) out[b] = sum + bfc[0];
}

extern "C" void kernel_launch(void* const* d_in, const int* in_sizes, int n_in,
                              void* d_out, int out_size, void* d_ws, size_t ws_size,
                              hipStream_t stream) {
    (void)in_sizes; (void)n_in; (void)out_size; (void)ws_size;
    const float* x   = (const float*)d_in[0];
    const float* Wih = (const float*)d_in[1];
    const float* Whh = (const float*)d_in[2];
    const float* bih = (const float*)d_in[3];
    const float* bhh = (const float*)d_in[4];
    const float* Wfc = (const float*)d_in[5];
    const float* bfc = (const float*)d_in[6];
    float* out = (float*)d_out;

    char* ws = (char*)d_ws;
    _Float16* W16   = (_Float16*)(ws + OFF_W16);
    _Float16* Wih16 = (_Float16*)(ws + OFF_WIH);
    float*    biasf = (float*)(ws + OFF_BIAS);
    _Float16* x16   = (_Float16*)(ws + OFF_X16);
    _Float16* h0b   = (_Float16*)(ws + OFF_H0);
    _Float16* h1b   = (_Float16*)(ws + OFF_H1);
    unsigned* ctrb  = (unsigned*)(ws + OFF_CTR);

    hipLaunchKernelGGL(prep_w, dim3((2048 * 512) / 256), dim3(256), 0, stream,
                       Wih, Whh, bih, bhh, W16, Wih16, biasf, h0b, ctrb);
    hipLaunchKernelGGL(prep_x, dim3((512 * 256 * 64) / 256), dim3(256), 0, stream, x, x16);
    hipLaunchKernelGGL(lstm_k, dim3(128), dim3(256), 0, stream,
                       W16, Wih16, biasf, x16, h0b, h1b, ctrb);
    // T=512 even: last write went to buffer 0
    hipLaunchKernelGGL(fc_k, dim3(256), dim3(64), 0, stream, h0b, Wfc, bfc, out);
}